// Round 1
// baseline (48838.092 us; speedup 1.0000x reference)
//
#include <hip/hip_runtime.h>
#include <math.h>

// ---- problem constants ----
constexpr int B    = 128;
constexpr int PAST = 256;
constexpr int FUT  = 128;
constexpr int D    = 128;
constexpr int RU   = 512;
constexpr int LD   = 128;
constexpr int TL   = 128;
constexpr int HDEC = RU + LD; // 640

__device__ __forceinline__ float sigm_(float x) { return 1.f / (1.f + __expf(-x)); }
__device__ __forceinline__ float tanh_(float x) {
    // tanh(x) = 1 - 2/(exp(2x)+1); safe at +/-inf of exp
    float e = __expf(2.f * x);
    return 1.f - 2.f / (e + 1.f);
}

// Fused GRU step: computes h_new = GRUCell(x_t, h) for a 16-row x 16-hidden tile.
// grid = (B/16, H/16), block = 256.
// Gate order (rows of Wih/Whh): [r (0..H), z (H..2H), n (2H..3H)].
template <int DX, int H>
__global__ __launch_bounds__(256) void gru_step(
    const float* __restrict__ x, int x_rstride,
    const float* __restrict__ h,
    const float* __restrict__ Wih,  // (3H, DX) row-major
    const float* __restrict__ Whh,  // (3H, H)  row-major
    const float* __restrict__ bih,  // (3H)
    const float* __restrict__ bhh,  // (3H)
    float* __restrict__ hnew)
{
    constexpr int W = DX + H;
    __shared__ float sxh[16][W + 4]; // +4 pad: keeps rows 16B-aligned, breaks bank aliasing

    const int r0  = blockIdx.x * 16;
    const int hd0 = blockIdx.y * 16;
    const int tid = threadIdx.x;

    // stage [x_tile | h_tile] (16 rows x W cols)
    for (int i = tid; i < 16 * W; i += 256) {
        int r = i / W, c = i - r * W;
        sxh[r][c] = (c < DX) ? x[(size_t)(r0 + r) * x_rstride + c]
                             : h[(size_t)(r0 + r) * H + (c - DX)];
    }
    __syncthreads();

    const int r  = tid >> 4;       // 0..15 row within tile
    const int c  = tid & 15;       // 0..15 hidden within tile
    const int hd = hd0 + c;

    const float4* wr_i = reinterpret_cast<const float4*>(Wih + (size_t)hd * DX);
    const float4* wz_i = reinterpret_cast<const float4*>(Wih + (size_t)(H + hd) * DX);
    const float4* wn_i = reinterpret_cast<const float4*>(Wih + (size_t)(2 * H + hd) * DX);
    const float4* wr_h = reinterpret_cast<const float4*>(Whh + (size_t)hd * H);
    const float4* wz_h = reinterpret_cast<const float4*>(Whh + (size_t)(H + hd) * H);
    const float4* wn_h = reinterpret_cast<const float4*>(Whh + (size_t)(2 * H + hd) * H);

    const float4* xv4 = reinterpret_cast<const float4*>(&sxh[r][0]);

    float ar = 0.f, az = 0.f, ani = 0.f, anh = 0.f;

    #pragma unroll 4
    for (int k = 0; k < DX / 4; ++k) {
        float4 xv = xv4[k];
        float4 a = wr_i[k], b = wz_i[k], n = wn_i[k];
        ar  = fmaf(xv.x, a.x, fmaf(xv.y, a.y, fmaf(xv.z, a.z, fmaf(xv.w, a.w, ar))));
        az  = fmaf(xv.x, b.x, fmaf(xv.y, b.y, fmaf(xv.z, b.z, fmaf(xv.w, b.w, az))));
        ani = fmaf(xv.x, n.x, fmaf(xv.y, n.y, fmaf(xv.z, n.z, fmaf(xv.w, n.w, ani))));
    }
    #pragma unroll 4
    for (int k = 0; k < H / 4; ++k) {
        float4 hv = xv4[DX / 4 + k];
        float4 a = wr_h[k], b = wz_h[k], n = wn_h[k];
        ar  = fmaf(hv.x, a.x, fmaf(hv.y, a.y, fmaf(hv.z, a.z, fmaf(hv.w, a.w, ar))));
        az  = fmaf(hv.x, b.x, fmaf(hv.y, b.y, fmaf(hv.z, b.z, fmaf(hv.w, b.w, az))));
        anh = fmaf(hv.x, n.x, fmaf(hv.y, n.y, fmaf(hv.z, n.z, fmaf(hv.w, n.w, anh))));
    }

    float rg = sigm_(ar + bih[hd] + bhh[hd]);
    float zg = sigm_(az + bih[H + hd] + bhh[H + hd]);
    float ng = tanh_(ani + bih[2 * H + hd] + rg * (anh + bhh[2 * H + hd]));
    float hv_old = sxh[r][DX + hd];
    hnew[(size_t)(r0 + r) * H + hd] = (1.f - zg) * ng + zg * hv_old;
}

// Y[m][n] = act( X[m,:K] . W[n,:K] + b[n] ); one thread per output element.
// act: 0 = none, 1 = leaky_relu(0.01), 2 = relu
__global__ __launch_bounds__(256) void linear_act(
    const float* __restrict__ X, const float* __restrict__ Wt,
    const float* __restrict__ bias, float* __restrict__ Y,
    int y_rstride, int M, int N, int K, int act)
{
    int idx = blockIdx.x * 256 + threadIdx.x;
    if (idx >= M * N) return;
    int m = idx / N, n = idx - m * N;
    const float4* xr = reinterpret_cast<const float4*>(X + (size_t)m * K);
    const float4* wr = reinterpret_cast<const float4*>(Wt + (size_t)n * K);
    float acc = 0.f;
    for (int k = 0; k < K / 4; ++k) {
        float4 a = xr[k], w = wr[k];
        acc = fmaf(a.x, w.x, fmaf(a.y, w.y, fmaf(a.z, w.z, fmaf(a.w, w.w, acc))));
    }
    acc += bias[n];
    if (act == 1)      acc = (acc > 0.f) ? acc : 0.01f * acc;
    else if (act == 2) acc = fmaxf(acc, 0.f);
    Y[(size_t)m * y_rstride + n] = acc;
}

// Y (M, ka+kb) = [A | Bp] row-wise concat
__global__ __launch_bounds__(256) void concat2(
    const float* __restrict__ A, int ka,
    const float* __restrict__ Bp, int kb,
    float* __restrict__ Y, int M)
{
    int w = ka + kb;
    int idx = blockIdx.x * 256 + threadIdx.x;
    if (idx >= M * w) return;
    int m = idx / w, c = idx - m * w;
    Y[idx] = (c < ka) ? A[(size_t)m * ka + c] : Bp[(size_t)m * kb + (c - ka)];
}

// z = z_mu + eps * exp(0.5 * z_logvar)
__global__ __launch_bounds__(256) void reparam(
    const float* __restrict__ zmu, const float* __restrict__ zlv,
    const float* __restrict__ eps, float* __restrict__ z, int n)
{
    int i = blockIdx.x * 256 + threadIdx.x;
    if (i < n) z[i] = zmu[i] + eps[i] * __expf(0.5f * zlv[i]);
}

extern "C" void kernel_launch(void* const* d_in, const int* in_sizes, int n_in,
                              void* d_out, int out_size, void* d_ws, size_t ws_size,
                              hipStream_t stream)
{
    const float* past    = (const float*)d_in[0];
    const float* future  = (const float*)d_in[1];
    const float* eps     = (const float*)d_in[2];
    const float* phi_Wih = (const float*)d_in[3];
    const float* phi_Whh = (const float*)d_in[4];
    const float* phi_bih = (const float*)d_in[5];
    const float* phi_bhh = (const float*)d_in[6];
    const float* xr_Wih  = (const float*)d_in[7];
    const float* xr_Whh  = (const float*)d_in[8];
    const float* xr_bih  = (const float*)d_in[9];
    const float* xr_bhh  = (const float*)d_in[10];
    const float* mu_W1   = (const float*)d_in[11];
    const float* mu_b1   = (const float*)d_in[12];
    const float* mu_W2   = (const float*)d_in[13];
    const float* mu_b2   = (const float*)d_in[14];
    const float* mu_W3   = (const float*)d_in[15];
    const float* mu_b3   = (const float*)d_in[16];
    const float* lv_W1   = (const float*)d_in[17];
    const float* lv_b1   = (const float*)d_in[18];
    const float* lv_W2   = (const float*)d_in[19];
    const float* lv_b2   = (const float*)d_in[20];
    const float* lv_W3   = (const float*)d_in[21];
    const float* lv_b3   = (const float*)d_in[22];
    const float* dec_Wih = (const float*)d_in[23];
    const float* dec_Whh = (const float*)d_in[24];
    const float* dec_bih = (const float*)d_in[25];
    const float* dec_bhh = (const float*)d_in[26];
    const float* fc_W    = (const float*)d_in[27];
    const float* fc_b    = (const float*)d_in[28];
    const float* out_W   = (const float*)d_in[29];
    const float* out_b   = (const float*)d_in[30];

    float* out = (float*)d_out;
    float* xmu = out;                         // (B, TL, D)
    float* zmu = out + (size_t)B * TL * D;    // (B, LD)
    float* zlv = zmu + (size_t)B * LD;        // (B, LD)

    float* ws  = (float*)d_ws;
    float* hA  = ws;                  // B*RU
    float* hB  = hA  + (size_t)B * RU;
    float* hxA = hB  + (size_t)B * RU;
    float* hxB = hxA + (size_t)B * RU;
    float* feat= hxB + (size_t)B * RU;       // B*2RU
    float* m1  = feat+ (size_t)B * 2 * RU;   // B*512
    float* m2  = m1  + (size_t)B * 512;      // B*256
    float* zb  = m2  + (size_t)B * 256;      // B*LD
    float* dA  = zb  + (size_t)B * LD;       // B*HDEC
    float* dB  = dA  + (size_t)B * HDEC;
    float* fcb = dB  + (size_t)B * HDEC;     // B*512

    (void)in_sizes; (void)n_in; (void)out_size; (void)ws_size;

    dim3 blk(256);

    // h0 = 0 for both encoders
    hipMemsetAsync(hA,  0, (size_t)B * RU * sizeof(float), stream);
    hipMemsetAsync(hxA, 0, (size_t)B * RU * sizeof(float), stream);

    // ---- phi encoder over past (256 steps) ----
    for (int t = 0; t < PAST; ++t) {
        const float* xt = past + (size_t)t * D;
        const float* hin  = (t & 1) ? hB : hA;
        float*       hout = (t & 1) ? hA : hB;
        gru_step<D, RU><<<dim3(B / 16, RU / 16), blk, 0, stream>>>(
            xt, PAST * D, hin, phi_Wih, phi_Whh, phi_bih, phi_bhh, hout);
    }
    // PAST is even -> final h_past in hA

    // ---- xr encoder over future (128 steps) ----
    for (int t = 0; t < FUT; ++t) {
        const float* xt = future + (size_t)t * D;
        const float* hin  = (t & 1) ? hxB : hxA;
        float*       hout = (t & 1) ? hxA : hxB;
        gru_step<D, RU><<<dim3(B / 16, RU / 16), blk, 0, stream>>>(
            xt, FUT * D, hin, xr_Wih, xr_Whh, xr_bih, xr_bhh, hout);
    }
    // FUT even -> final h_future in hxA

    // ---- features = [h_past | h_future] ----
    concat2<<<dim3((B * 2 * RU + 255) / 256), blk, 0, stream>>>(hA, RU, hxA, RU, feat, B);

    // ---- mu MLP ----
    linear_act<<<dim3((B * 512 + 255) / 256), blk, 0, stream>>>(feat, mu_W1, mu_b1, m1, 512, B, 512, 2 * RU, 1);
    linear_act<<<dim3((B * 256 + 255) / 256), blk, 0, stream>>>(m1, mu_W2, mu_b2, m2, 256, B, 256, 512, 1);
    linear_act<<<dim3((B * LD  + 255) / 256), blk, 0, stream>>>(m2, mu_W3, mu_b3, zmu, LD, B, LD, 256, 0);
    // ---- logvar MLP ----
    linear_act<<<dim3((B * 512 + 255) / 256), blk, 0, stream>>>(feat, lv_W1, lv_b1, m1, 512, B, 512, 2 * RU, 1);
    linear_act<<<dim3((B * 256 + 255) / 256), blk, 0, stream>>>(m1, lv_W2, lv_b2, m2, 256, B, 256, 512, 1);
    linear_act<<<dim3((B * LD  + 255) / 256), blk, 0, stream>>>(m2, lv_W3, lv_b3, zlv, LD, B, LD, 256, 0);

    // ---- z = z_mu + eps*exp(0.5*logvar) ----
    reparam<<<dim3((B * LD + 255) / 256), blk, 0, stream>>>(zmu, zlv, eps, zb, B * LD);

    // ---- dec_h0 = [h_past | z] ----
    concat2<<<dim3((B * HDEC + 255) / 256), blk, 0, stream>>>(hA, RU, zb, LD, dA, B);

    // ---- decoder: 128 steps of GRU -> fc(relu) -> out ----
    for (int t = 0; t < TL; ++t) {
        const float* xin;
        int xstride;
        if (t == 0) { xin = past + (size_t)(PAST - 1) * D; xstride = PAST * D; }
        else        { xin = xmu + (size_t)(t - 1) * D;     xstride = TL * D; }
        const float* hin  = (t & 1) ? dB : dA;
        float*       hout = (t & 1) ? dA : dB;
        gru_step<D, HDEC><<<dim3(B / 16, HDEC / 16), blk, 0, stream>>>(
            xin, xstride, hin, dec_Wih, dec_Whh, dec_bih, dec_bhh, hout);
        // fc = relu(h @ fc_W.T + fc_b)
        linear_act<<<dim3((B * 512 + 255) / 256), blk, 0, stream>>>(hout, fc_W, fc_b, fcb, 512, B, 512, HDEC, 2);
        // x_mu[:, t, :] = fc @ out_W.T + out_b
        linear_act<<<dim3((B * D + 255) / 256), blk, 0, stream>>>(fcb, out_W, out_b, xmu + (size_t)t * D, TL * D, B, D, 512, 0);
    }
}

// Round 2
// 15026.439 us; speedup vs baseline: 3.2501x; 3.2501x over previous
//
#include <hip/hip_runtime.h>
#include <math.h>

// ---- problem constants ----
constexpr int B    = 128;
constexpr int PAST = 256;
constexpr int FUT  = 128;
constexpr int D    = 128;
constexpr int RU   = 512;
constexpr int LD   = 128;
constexpr int TL   = 128;
constexpr int HDEC = 640;

typedef __bf16 bf16x8 __attribute__((ext_vector_type(8)));
typedef float  f32x4  __attribute__((ext_vector_type(4)));
typedef unsigned short u16x8 __attribute__((ext_vector_type(8)));

__device__ __forceinline__ unsigned short f2bf(float f) {
    unsigned int x = __float_as_uint(f);
    x = (x + 0x7fffu + ((x >> 16) & 1u)) >> 16;
    return (unsigned short)x;
}
__device__ __forceinline__ float bf2f(unsigned short u) {
    return __uint_as_float(((unsigned int)u) << 16);
}
__device__ __forceinline__ float sigm_(float x) { return 1.f / (1.f + __expf(-x)); }
__device__ __forceinline__ float tanh_(float x) {
    float e = __expf(2.f * x);
    return 1.f - 2.f / (e + 1.f);
}
__device__ __forceinline__ bf16x8 ldsfrag(const unsigned short* p) {
    return *reinterpret_cast<const bf16x8*>(p);
}
__device__ __forceinline__ f32x4 mfma16(bf16x8 a, bf16x8 b, f32x4 c) {
    return __builtin_amdgcn_mfma_f32_16x16x32_bf16(a, b, c, 0, 0, 0);
}

// ======================= weight conversion =======================
__global__ __launch_bounds__(256) void split_plain(
    const float* __restrict__ W, unsigned short* __restrict__ hi,
    unsigned short* __restrict__ lo, int n)
{
    for (int i = blockIdx.x * 256 + threadIdx.x; i < n; i += gridDim.x * 256) {
        float v = W[i];
        unsigned short h = f2bf(v);
        hi[i] = h;
        lo[i] = f2bf(v - bf2f(h));
    }
}

// packed [Wih | Whh]: (N3, DXc+Hc), split to hi/lo bf16
__global__ __launch_bounds__(256) void split_pack(
    const float* __restrict__ Wih, const float* __restrict__ Whh,
    int DXc, int Hc, int N3,
    unsigned short* __restrict__ hi, unsigned short* __restrict__ lo)
{
    int K = DXc + Hc;
    int total = N3 * K;
    for (int i = blockIdx.x * 256 + threadIdx.x; i < total; i += gridDim.x * 256) {
        int n = i / K, k = i - n * K;
        float v = (k < DXc) ? Wih[(size_t)n * DXc + k]
                            : Whh[(size_t)n * Hc + (k - DXc)];
        unsigned short h = f2bf(v);
        hi[i] = h;
        lo[i] = f2bf(v - bf2f(h));
    }
}

// ======================= fused GRU step (MFMA bf16x3) =======================
// acc sets: 0=r, 1=z, 2=n(x-part), 3=n(h-part)
struct StepArgs {
    const float* x;  int sx;       // x_t rows (B x DX), row stride sx
    const float* h_in;             // (B, H)
    const unsigned short* Whi;     // packed (3H, DX+H) bf16 hi
    const unsigned short* Wlo;
    const float* bih; const float* bhh;  // (3H)
    float* h_out;
};

template<int NSET>
__device__ __forceinline__ void step_compute(
    const unsigned short* sA0, const unsigned short* sA1,
    const unsigned short* sW0, const unsigned short* sW1,
    int nlocal, int arow, int koff, f32x4 (&acc)[4][4])
{
    constexpr int LDR = 40;
    bf16x8 wh[3], wl[3];
    #pragma unroll
    for (int g = 0; g < 3; ++g) {
        wh[g] = ldsfrag(&sW0[(g * 64 + nlocal) * LDR + koff]);
        wl[g] = ldsfrag(&sW1[(g * 64 + nlocal) * LDR + koff]);
    }
    #pragma unroll
    for (int mf = 0; mf < 4; ++mf) {
        bf16x8 ah = ldsfrag(&sA0[(mf * 16 + arow) * LDR + koff]);
        bf16x8 al = ldsfrag(&sA1[(mf * 16 + arow) * LDR + koff]);
        acc[mf][0] = mfma16(ah, wh[0], acc[mf][0]);
        acc[mf][0] = mfma16(ah, wl[0], acc[mf][0]);
        acc[mf][0] = mfma16(al, wh[0], acc[mf][0]);
        acc[mf][1] = mfma16(ah, wh[1], acc[mf][1]);
        acc[mf][1] = mfma16(ah, wl[1], acc[mf][1]);
        acc[mf][1] = mfma16(al, wh[1], acc[mf][1]);
        acc[mf][NSET] = mfma16(ah, wh[2], acc[mf][NSET]);
        acc[mf][NSET] = mfma16(ah, wl[2], acc[mf][NSET]);
        acc[mf][NSET] = mfma16(al, wh[2], acc[mf][NSET]);
    }
}

// grid: (2 m-tiles, H/64 h-tiles, 1|2 encoders), block 256 (4 waves)
// wave w owns h-cols hc0 + w*16 .. +15 for all 64 m-rows of its m-tile.
template<int H, int DX>
__global__ __launch_bounds__(256, 1) void gru_step_mfma(StepArgs A0, StepArgs A1)
{
    constexpr int K   = DX + H;
    constexpr int NC  = K / 32;     // 32-wide K chunks
    constexpr int XC  = DX / 32;    // chunks sourced from x
    constexpr int LDR = 40;         // ushorts/row: 32 data + 8 pad (80B, 16B-aligned)

    __shared__ unsigned short sA[2][64 * LDR];
    __shared__ unsigned short sW[2][3 * 64 * LDR];

    const StepArgs A = (blockIdx.z == 0) ? A0 : A1;
    const int m0   = blockIdx.x * 64;
    const int hc0  = blockIdx.y * 64;
    const int tid  = threadIdx.x;
    const int lane = tid & 63;
    const int w    = tid >> 6;
    const int arow = lane & 15;
    const int koff = (lane >> 4) * 8;
    const int nlocal = w * 16 + arow;

    f32x4 acc[4][4];
    #pragma unroll
    for (int i = 0; i < 4; ++i)
        #pragma unroll
        for (int j = 0; j < 4; ++j) acc[i][j] = f32x4{0.f, 0.f, 0.f, 0.f};

    float4 ar[2];
    u16x8  wreg[6];

    auto load_chunk = [&](int c) {
        const int k0 = c * 32;
        // A: 64 rows x 8 float4  (512 ids / 256 thr = 2 each)
        #pragma unroll
        for (int j = 0; j < 2; ++j) {
            int id = tid + j * 256;
            int row = id >> 3, c4 = id & 7;
            const float* src = (k0 < DX)
                ? (A.x + (size_t)(m0 + row) * A.sx + (k0 + c4 * 4))
                : (A.h_in + (size_t)(m0 + row) * H + (k0 - DX + c4 * 4));
            ar[j] = *reinterpret_cast<const float4*>(src);
        }
        // W: 2 halves x 3 gates x 64 rows x 4 u16x8 = 1536 ids / 256 = 6 each
        #pragma unroll
        for (int j = 0; j < 6; ++j) {
            int id = tid + j * 256;
            int half = (id >= 768) ? 1 : 0;
            int rem = id - half * 768;
            int gate = rem >> 8;
            int rr = (rem >> 2) & 63;
            int c8 = rem & 3;
            const unsigned short* Wp = half ? A.Wlo : A.Whi;
            wreg[j] = *reinterpret_cast<const u16x8*>(
                Wp + (size_t)(gate * H + hc0 + rr) * K + k0 + c8 * 8);
        }
    };

    auto write_chunk = [&]() {
        #pragma unroll
        for (int j = 0; j < 2; ++j) {
            int id = tid + j * 256;
            int row = id >> 3, c4 = id & 7;
            float v[4] = {ar[j].x, ar[j].y, ar[j].z, ar[j].w};
            unsigned short hs[4], ls[4];
            #pragma unroll
            for (int q = 0; q < 4; ++q) {
                hs[q] = f2bf(v[q]);
                ls[q] = f2bf(v[q] - bf2f(hs[q]));
            }
            uint2 hp, lp;
            hp.x = (unsigned)hs[0] | ((unsigned)hs[1] << 16);
            hp.y = (unsigned)hs[2] | ((unsigned)hs[3] << 16);
            lp.x = (unsigned)ls[0] | ((unsigned)ls[1] << 16);
            lp.y = (unsigned)ls[2] | ((unsigned)ls[3] << 16);
            *reinterpret_cast<uint2*>(&sA[0][row * LDR + c4 * 4]) = hp;
            *reinterpret_cast<uint2*>(&sA[1][row * LDR + c4 * 4]) = lp;
        }
        #pragma unroll
        for (int j = 0; j < 6; ++j) {
            int id = tid + j * 256;
            int half = (id >= 768) ? 1 : 0;
            int rem = id - half * 768;
            int gate = rem >> 8;
            int rr = (rem >> 2) & 63;
            int c8 = rem & 3;
            *reinterpret_cast<u16x8*>(&sW[half][(gate * 64 + rr) * LDR + c8 * 8]) = wreg[j];
        }
    };

    load_chunk(0);
    write_chunk();
    __syncthreads();
    for (int c = 0; c < NC; ++c) {
        if (c + 1 < NC) load_chunk(c + 1);   // overlap global latency with MFMA below
        if (c < XC) step_compute<2>(sA[0], sA[1], sW[0], sW[1], nlocal, arow, koff, acc);
        else        step_compute<3>(sA[0], sA[1], sW[0], sW[1], nlocal, arow, koff, acc);
        __syncthreads();
        if (c + 1 < NC) { write_chunk(); __syncthreads(); }
    }

    // epilogue: gates + h update
    const int hc = hc0 + nlocal;
    const float bir = A.bih[hc],         bhr = A.bhh[hc];
    const float biz = A.bih[H + hc],     bhz = A.bhh[H + hc];
    const float bin = A.bih[2 * H + hc], bhn = A.bhh[2 * H + hc];
    #pragma unroll
    for (int mf = 0; mf < 4; ++mf) {
        #pragma unroll
        for (int r = 0; r < 4; ++r) {
            int m = m0 + mf * 16 + (lane >> 4) * 4 + r;
            float rg = sigm_(acc[mf][0][r] + bir + bhr);
            float zg = sigm_(acc[mf][1][r] + biz + bhz);
            float ng = tanh_((acc[mf][2][r] + bin) + rg * (acc[mf][3][r] + bhn));
            float ho = A.h_in[(size_t)m * H + hc];
            A.h_out[(size_t)m * H + hc] = (1.f - zg) * ng + zg * ho;
        }
    }
}

// ======================= generic GEMM: C = act(A @ W.T + b) =======================
// A fp32 (M x K, lda), W bf16 hi/lo (N x K), C fp32 (ldc). grid (M/64, N/128), 256 thr.
__global__ __launch_bounds__(256, 1) void gemm_mfma(
    const float* __restrict__ A, int lda,
    const unsigned short* __restrict__ Whi, const unsigned short* __restrict__ Wlo,
    int K, const float* __restrict__ bias,
    float* __restrict__ C, int ldc, int act)
{
    constexpr int LDR = 72;   // 64 data + 8 pad ushorts (144B rows)
    __shared__ unsigned short sA[2][64 * LDR];
    __shared__ unsigned short sW[2][128 * LDR];

    const int m0 = blockIdx.x * 64;
    const int n0 = blockIdx.y * 128;
    const int tid = threadIdx.x;
    const int lane = tid & 63;
    const int w = tid >> 6;
    const int arow = lane & 15;
    const int koff = (lane >> 4) * 8;

    f32x4 acc[4][2];
    #pragma unroll
    for (int i = 0; i < 4; ++i) { acc[i][0] = f32x4{0,0,0,0}; acc[i][1] = f32x4{0,0,0,0}; }

    float4 ar[4];
    u16x8  wreg[8];
    const int NC = K / 64;

    auto load_chunk = [&](int c) {
        const int k0 = c * 64;
        #pragma unroll
        for (int j = 0; j < 4; ++j) {
            int id = tid + j * 256;
            int row = id >> 4, c4 = id & 15;
            ar[j] = *reinterpret_cast<const float4*>(A + (size_t)(m0 + row) * lda + k0 + c4 * 4);
        }
        #pragma unroll
        for (int j = 0; j < 8; ++j) {
            int id = tid + j * 256;
            int half = id >> 10;
            int rem = id & 1023;
            int row = rem >> 3, c8 = rem & 7;
            const unsigned short* Wp = half ? Wlo : Whi;
            wreg[j] = *reinterpret_cast<const u16x8*>(
                Wp + (size_t)(n0 + row) * K + k0 + c8 * 8);
        }
    };
    auto write_chunk = [&]() {
        #pragma unroll
        for (int j = 0; j < 4; ++j) {
            int id = tid + j * 256;
            int row = id >> 4, c4 = id & 15;
            float v[4] = {ar[j].x, ar[j].y, ar[j].z, ar[j].w};
            unsigned short hs[4], ls[4];
            #pragma unroll
            for (int q = 0; q < 4; ++q) {
                hs[q] = f2bf(v[q]);
                ls[q] = f2bf(v[q] - bf2f(hs[q]));
            }
            uint2 hp, lp;
            hp.x = (unsigned)hs[0] | ((unsigned)hs[1] << 16);
            hp.y = (unsigned)hs[2] | ((unsigned)hs[3] << 16);
            lp.x = (unsigned)ls[0] | ((unsigned)ls[1] << 16);
            lp.y = (unsigned)ls[2] | ((unsigned)ls[3] << 16);
            *reinterpret_cast<uint2*>(&sA[0][row * LDR + c4 * 4]) = hp;
            *reinterpret_cast<uint2*>(&sA[1][row * LDR + c4 * 4]) = lp;
        }
        #pragma unroll
        for (int j = 0; j < 8; ++j) {
            int id = tid + j * 256;
            int half = id >> 10;
            int rem = id & 1023;
            int row = rem >> 3, c8 = rem & 7;
            *reinterpret_cast<u16x8*>(&sW[half][row * LDR + c8 * 8]) = wreg[j];
        }
    };

    load_chunk(0);
    write_chunk();
    __syncthreads();
    for (int c = 0; c < NC; ++c) {
        if (c + 1 < NC) load_chunk(c + 1);
        #pragma unroll
        for (int ks = 0; ks < 2; ++ks) {
            bf16x8 wh[2], wl[2];
            #pragma unroll
            for (int nf = 0; nf < 2; ++nf) {
                wh[nf] = ldsfrag(&sW[0][(w * 32 + nf * 16 + arow) * LDR + ks * 32 + koff]);
                wl[nf] = ldsfrag(&sW[1][(w * 32 + nf * 16 + arow) * LDR + ks * 32 + koff]);
            }
            #pragma unroll
            for (int mf = 0; mf < 4; ++mf) {
                bf16x8 ah = ldsfrag(&sA[0][(mf * 16 + arow) * LDR + ks * 32 + koff]);
                bf16x8 al = ldsfrag(&sA[1][(mf * 16 + arow) * LDR + ks * 32 + koff]);
                #pragma unroll
                for (int nf = 0; nf < 2; ++nf) {
                    acc[mf][nf] = mfma16(ah, wh[nf], acc[mf][nf]);
                    acc[mf][nf] = mfma16(ah, wl[nf], acc[mf][nf]);
                    acc[mf][nf] = mfma16(al, wh[nf], acc[mf][nf]);
                }
            }
        }
        __syncthreads();
        if (c + 1 < NC) { write_chunk(); __syncthreads(); }
    }

    #pragma unroll
    for (int mf = 0; mf < 4; ++mf) {
        #pragma unroll
        for (int nf = 0; nf < 2; ++nf) {
            int n = n0 + w * 32 + nf * 16 + arow;
            float bv = bias[n];
            #pragma unroll
            for (int r = 0; r < 4; ++r) {
                int m = m0 + mf * 16 + (lane >> 4) * 4 + r;
                float v = acc[mf][nf][r] + bv;
                if (act == 1)      v = (v > 0.f) ? v : 0.01f * v;
                else if (act == 2) v = fmaxf(v, 0.f);
                C[(size_t)m * ldc + n] = v;
            }
        }
    }
}

// ======================= small helpers =======================
__global__ __launch_bounds__(256) void concat2(
    const float* __restrict__ A, int ka,
    const float* __restrict__ Bp, int kb,
    float* __restrict__ Y, int M)
{
    int wdt = ka + kb;
    int idx = blockIdx.x * 256 + threadIdx.x;
    if (idx >= M * wdt) return;
    int m = idx / wdt, c = idx - m * wdt;
    Y[idx] = (c < ka) ? A[(size_t)m * ka + c] : Bp[(size_t)m * kb + (c - ka)];
}

__global__ __launch_bounds__(256) void reparam(
    const float* __restrict__ zmu, const float* __restrict__ zlv,
    const float* __restrict__ eps, float* __restrict__ z, int n)
{
    int i = blockIdx.x * 256 + threadIdx.x;
    if (i < n) z[i] = zmu[i] + eps[i] * __expf(0.5f * zlv[i]);
}

// ======================= host =======================
extern "C" void kernel_launch(void* const* d_in, const int* in_sizes, int n_in,
                              void* d_out, int out_size, void* d_ws, size_t ws_size,
                              hipStream_t stream)
{
    const float* past    = (const float*)d_in[0];
    const float* future  = (const float*)d_in[1];
    const float* eps     = (const float*)d_in[2];
    const float* phi_Wih = (const float*)d_in[3];
    const float* phi_Whh = (const float*)d_in[4];
    const float* phi_bih = (const float*)d_in[5];
    const float* phi_bhh = (const float*)d_in[6];
    const float* xr_Wih  = (const float*)d_in[7];
    const float* xr_Whh  = (const float*)d_in[8];
    const float* xr_bih  = (const float*)d_in[9];
    const float* xr_bhh  = (const float*)d_in[10];
    const float* mu_W1   = (const float*)d_in[11];
    const float* mu_b1   = (const float*)d_in[12];
    const float* mu_W2   = (const float*)d_in[13];
    const float* mu_b2   = (const float*)d_in[14];
    const float* mu_W3   = (const float*)d_in[15];
    const float* mu_b3   = (const float*)d_in[16];
    const float* lv_W1   = (const float*)d_in[17];
    const float* lv_b1   = (const float*)d_in[18];
    const float* lv_W2   = (const float*)d_in[19];
    const float* lv_b2   = (const float*)d_in[20];
    const float* lv_W3   = (const float*)d_in[21];
    const float* lv_b3   = (const float*)d_in[22];
    const float* dec_Wih = (const float*)d_in[23];
    const float* dec_Whh = (const float*)d_in[24];
    const float* dec_bih = (const float*)d_in[25];
    const float* dec_bhh = (const float*)d_in[26];
    const float* fc_W    = (const float*)d_in[27];
    const float* fc_b    = (const float*)d_in[28];
    const float* out_W   = (const float*)d_in[29];
    const float* out_b   = (const float*)d_in[30];
    (void)in_sizes; (void)n_in; (void)out_size; (void)ws_size;

    float* out = (float*)d_out;
    float* xmu = out;                          // (B, TL, D)
    float* zmu = out + (size_t)B * TL * D;     // (B, LD)
    float* zlv = zmu + (size_t)B * LD;

    // ---- workspace carve (256B aligned slices) ----
    char* p = (char*)d_ws;
    auto aus = [&](size_t n) { unsigned short* r = (unsigned short*)p; p += ((n * 2 + 255) / 256) * 256; return r; };
    auto af  = [&](size_t n) { float* r = (float*)p; p += ((n * 4 + 255) / 256) * 256; return r; };

    unsigned short* phiWhi = aus((size_t)3 * RU * (D + RU));
    unsigned short* phiWlo = aus((size_t)3 * RU * (D + RU));
    unsigned short* xrWhi  = aus((size_t)3 * RU * (D + RU));
    unsigned short* xrWlo  = aus((size_t)3 * RU * (D + RU));
    unsigned short* decWhi = aus((size_t)3 * HDEC * (D + HDEC));
    unsigned short* decWlo = aus((size_t)3 * HDEC * (D + HDEC));
    unsigned short* mW1hi = aus(512 * 1024), *mW1lo = aus(512 * 1024);
    unsigned short* mW2hi = aus(256 * 512),  *mW2lo = aus(256 * 512);
    unsigned short* mW3hi = aus(128 * 256),  *mW3lo = aus(128 * 256);
    unsigned short* lW1hi = aus(512 * 1024), *lW1lo = aus(512 * 1024);
    unsigned short* lW2hi = aus(256 * 512),  *lW2lo = aus(256 * 512);
    unsigned short* lW3hi = aus(128 * 256),  *lW3lo = aus(128 * 256);
    unsigned short* fcWhi = aus(512 * 640),  *fcWlo = aus(512 * 640);
    unsigned short* oWhi  = aus(128 * 512),  *oWlo  = aus(128 * 512);

    float* hA  = af((size_t)B * RU);
    float* hB  = af((size_t)B * RU);
    float* hxA = af((size_t)B * RU);
    float* hxB = af((size_t)B * RU);
    float* dA  = af((size_t)B * HDEC);
    float* dB  = af((size_t)B * HDEC);
    float* feat= af((size_t)B * 2 * RU);
    float* m1  = af((size_t)B * 512);
    float* m2  = af((size_t)B * 256);
    float* zb  = af((size_t)B * LD);
    float* fcb = af((size_t)B * 512);

    dim3 blk(256);

    // ---- weight split/pack ----
    split_pack<<<512, blk, 0, stream>>>(phi_Wih, phi_Whh, D, RU, 3 * RU, phiWhi, phiWlo);
    split_pack<<<512, blk, 0, stream>>>(xr_Wih,  xr_Whh,  D, RU, 3 * RU, xrWhi,  xrWlo);
    split_pack<<<512, blk, 0, stream>>>(dec_Wih, dec_Whh, D, HDEC, 3 * HDEC, decWhi, decWlo);
    split_plain<<<512, blk, 0, stream>>>(mu_W1, mW1hi, mW1lo, 512 * 1024);
    split_plain<<<256, blk, 0, stream>>>(mu_W2, mW2hi, mW2lo, 256 * 512);
    split_plain<<<128, blk, 0, stream>>>(mu_W3, mW3hi, mW3lo, 128 * 256);
    split_plain<<<512, blk, 0, stream>>>(lv_W1, lW1hi, lW1lo, 512 * 1024);
    split_plain<<<256, blk, 0, stream>>>(lv_W2, lW2hi, lW2lo, 256 * 512);
    split_plain<<<128, blk, 0, stream>>>(lv_W3, lW3hi, lW3lo, 128 * 256);
    split_plain<<<512, blk, 0, stream>>>(fc_W, fcWhi, fcWlo, 512 * 640);
    split_plain<<<128, blk, 0, stream>>>(out_W, oWhi, oWlo, 128 * 512);

    hipMemsetAsync(hA,  0, (size_t)B * RU * sizeof(float), stream);
    hipMemsetAsync(hxA, 0, (size_t)B * RU * sizeof(float), stream);

    // ---- encoders (phi: 256 steps, xr: 128 steps; first 128 fused) ----
    for (int t = 0; t < PAST; ++t) {
        const float* phin  = (t & 1) ? hB : hA;
        float*       phout = (t & 1) ? hA : hB;
        StepArgs pa{past + (size_t)t * D, PAST * D, phin, phiWhi, phiWlo, phi_bih, phi_bhh, phout};
        if (t < FUT) {
            const float* xin  = (t & 1) ? hxB : hxA;
            float*       xout = (t & 1) ? hxA : hxB;
            StepArgs xa{future + (size_t)t * D, FUT * D, xin, xrWhi, xrWlo, xr_bih, xr_bhh, xout};
            gru_step_mfma<RU, D><<<dim3(2, RU / 64, 2), blk, 0, stream>>>(pa, xa);
        } else {
            gru_step_mfma<RU, D><<<dim3(2, RU / 64, 1), blk, 0, stream>>>(pa, pa);
        }
    }
    // finals: h_past in hA, h_future in hxA (even step counts)

    concat2<<<dim3((B * 2 * RU + 255) / 256), blk, 0, stream>>>(hA, RU, hxA, RU, feat, B);

    // ---- mu / logvar MLPs ----
    gemm_mfma<<<dim3(2, 4), blk, 0, stream>>>(feat, 2 * RU, mW1hi, mW1lo, 1024, mu_b1, m1, 512, 1);
    gemm_mfma<<<dim3(2, 2), blk, 0, stream>>>(m1, 512, mW2hi, mW2lo, 512, mu_b2, m2, 256, 1);
    gemm_mfma<<<dim3(2, 1), blk, 0, stream>>>(m2, 256, mW3hi, mW3lo, 256, mu_b3, zmu, LD, 0);
    gemm_mfma<<<dim3(2, 4), blk, 0, stream>>>(feat, 2 * RU, lW1hi, lW1lo, 1024, lv_b1, m1, 512, 1);
    gemm_mfma<<<dim3(2, 2), blk, 0, stream>>>(m1, 512, lW2hi, lW2lo, 512, lv_b2, m2, 256, 1);
    gemm_mfma<<<dim3(2, 1), blk, 0, stream>>>(m2, 256, lW3hi, lW3lo, 256, lv_b3, zlv, LD, 0);

    reparam<<<dim3((B * LD + 255) / 256), blk, 0, stream>>>(zmu, zlv, eps, zb, B * LD);
    concat2<<<dim3((B * HDEC + 255) / 256), blk, 0, stream>>>(hA, RU, zb, LD, dA, B);

    // ---- decoder: GRU step -> fc(relu) -> out, feedback through xmu ----
    for (int t = 0; t < TL; ++t) {
        const float* xin; int sx;
        if (t == 0) { xin = past + (size_t)(PAST - 1) * D; sx = PAST * D; }
        else        { xin = xmu + (size_t)(t - 1) * D;     sx = TL * D; }
        const float* hin  = (t & 1) ? dB : dA;
        float*       hout = (t & 1) ? dA : dB;
        StepArgs da{xin, sx, hin, decWhi, decWlo, dec_bih, dec_bhh, hout};
        gru_step_mfma<HDEC, D><<<dim3(2, HDEC / 64, 1), blk, 0, stream>>>(da, da);
        gemm_mfma<<<dim3(2, 4), blk, 0, stream>>>(hout, HDEC, fcWhi, fcWlo, HDEC, fc_b, fcb, 512, 2);
        gemm_mfma<<<dim3(2, 1), blk, 0, stream>>>(fcb, 512, oWhi, oWlo, 512, out_b, xmu + (size_t)t * D, TL * D, 0);
    }
}